// Round 1
// baseline (782.930 us; speedup 1.0000x reference)
//
#include <hip/hip_runtime.h>

// Problem constants (match reference).
constexpr int Bt  = 131072;
constexpr int OBS = 194;
constexpr int Hd  = 64;
constexpr int Ad  = 5;
constexpr int NT  = 128;   // threads per block (2 waves)

__device__ __forceinline__ float fast_tanh(float v) {
    v = fminf(fmaxf(v, -15.f), 15.f);
    float e = __expf(2.f * v);
    return (e - 1.f) * __builtin_amdgcn_rcpf(e + 1.f);
}

// Two-layer MLP: acc = tanh( tanh(x*Wa + ba) * Wb + bb ), with the hidden
// vector round-tripped through LDS (dynamic k-index in 2nd GEMM).
// hcol points at &hbuf[0][t]; row stride is NT floats.
__device__ __forceinline__ void mlp2(
    const float2* __restrict__ xrow,
    float* __restrict__ hcol,
    const float* __restrict__ Wa, const float* __restrict__ ba,
    const float* __restrict__ Wb, const float* __restrict__ bb,
    float (&acc)[Hd])
{
    #pragma unroll
    for (int j = 0; j < Hd; ++j) acc[j] = ba[j];

    #pragma unroll 1
    for (int k2 = 0; k2 < OBS / 2; ++k2) {
        float2 xv = xrow[k2];
        const float* __restrict__ w0 = Wa + (2 * k2) * Hd;
        #pragma unroll
        for (int j = 0; j < Hd; ++j) acc[j] = fmaf(xv.x, w0[j], acc[j]);
        #pragma unroll
        for (int j = 0; j < Hd; ++j) acc[j] = fmaf(xv.y, w0[Hd + j], acc[j]);
    }

    // tanh -> LDS (own column only; no barrier needed, same-thread RAW)
    #pragma unroll
    for (int j = 0; j < Hd; ++j) hcol[j * NT] = fast_tanh(acc[j]);

    #pragma unroll
    for (int j = 0; j < Hd; ++j) acc[j] = bb[j];

    #pragma unroll 1
    for (int k = 0; k < Hd; ++k) {
        float hv = hcol[k * NT];
        const float* __restrict__ w = Wb + k * Hd;
        #pragma unroll
        for (int j = 0; j < Hd; ++j) acc[j] = fmaf(hv, w[j], acc[j]);
    }

    #pragma unroll
    for (int j = 0; j < Hd; ++j) acc[j] = fast_tanh(acc[j]);
}

__global__ void __launch_bounds__(NT) fused_ac(
    const float* __restrict__ x, const int* __restrict__ act_in,
    const float* __restrict__ W1, const float* __restrict__ b1,
    const float* __restrict__ W2, const float* __restrict__ b2,
    const float* __restrict__ Wh, const float* __restrict__ bh,
    const float* __restrict__ Wc1, const float* __restrict__ bc1,
    const float* __restrict__ Wc2, const float* __restrict__ bc2,
    const float* __restrict__ Wc3, const float* __restrict__ bc3,
    float* __restrict__ out)
{
    __shared__ float hbuf[Hd][NT];
    const int t = threadIdx.x;
    const int b = blockIdx.x * NT + t;
    const float* xr = x + (size_t)b * OBS;
    const float2* __restrict__ xrow = reinterpret_cast<const float2*>(xr);
    float* hcol = &hbuf[0][t];

    float acc[Hd];

    // ---------------- actor ----------------
    mlp2(xrow, hcol, W1, b1, W2, b2, acc);

    // event routing: argmax of first 3 obs dims (first-occurrence ties)
    float x0 = xr[0], x1 = xr[1], x2 = xr[2];
    int ev = 0; float best = x0;
    if (x1 > best) { best = x1; ev = 1; }
    if (x2 > best) { ev = 2; }

    // head logits for the selected event only
    float l[Ad];
    const float* __restrict__ whp = Wh + ev * (Hd * Ad);
    const float* __restrict__ bhp = bh + ev * Ad;
    #pragma unroll
    for (int a = 0; a < Ad; ++a) l[a] = bhp[a];
    #pragma unroll
    for (int j = 0; j < Hd; ++j) {
        float fv = acc[j];
        #pragma unroll
        for (int a = 0; a < Ad; ++a) l[a] = fmaf(fv, whp[j * Ad + a], l[a]);
    }

    // log-softmax over 5
    float m = l[0];
    #pragma unroll
    for (int a = 1; a < Ad; ++a) m = fmaxf(m, l[a]);
    float se = 0.f;
    #pragma unroll
    for (int a = 0; a < Ad; ++a) se += __expf(l[a] - m);
    float lse = __logf(se) + m;

    int act = act_in[b];
    float lsel = l[0];
    #pragma unroll
    for (int a = 1; a < Ad; ++a) lsel = (act == a) ? l[a] : lsel;
    float logp = lsel - lse;

    float ent = 0.f;
    #pragma unroll
    for (int a = 0; a < Ad; ++a) {
        float lp = l[a] - lse;
        ent -= __expf(lp) * lp;
    }

    // ---------------- critic ----------------
    mlp2(xrow, hcol, Wc1, bc1, Wc2, bc2, acc);
    float v = bc3[0];
    #pragma unroll
    for (int j = 0; j < Hd; ++j) v = fmaf(acc[j], Wc3[j], v);

    // ---------------- outputs (action, logp, entropy, value) ----------------
    out[b]          = (float)act;
    out[Bt + b]     = logp;
    out[2 * Bt + b] = ent;
    out[3 * Bt + b] = v;
}

extern "C" void kernel_launch(void* const* d_in, const int* in_sizes, int n_in,
                              void* d_out, int out_size, void* d_ws, size_t ws_size,
                              hipStream_t stream) {
    const float* x   = (const float*)d_in[0];
    const int*   act = (const int*)  d_in[1];
    const float* W1  = (const float*)d_in[2];
    const float* b1  = (const float*)d_in[3];
    const float* W2  = (const float*)d_in[4];
    const float* b2  = (const float*)d_in[5];
    const float* Wh  = (const float*)d_in[6];
    const float* bh  = (const float*)d_in[7];
    const float* Wc1 = (const float*)d_in[8];
    const float* bc1 = (const float*)d_in[9];
    const float* Wc2 = (const float*)d_in[10];
    const float* bc2 = (const float*)d_in[11];
    const float* Wc3 = (const float*)d_in[12];
    const float* bc3 = (const float*)d_in[13];
    float* out = (float*)d_out;

    dim3 grid(Bt / NT), block(NT);
    hipLaunchKernelGGL(fused_ac, grid, block, 0, stream,
                       x, act, W1, b1, W2, b2, Wh, bh,
                       Wc1, bc1, Wc2, bc2, Wc3, bc3, out);
}

// Round 2
// 212.022 us; speedup vs baseline: 3.6927x; 3.6927x over previous
//
#include <hip/hip_runtime.h>
#include <hip/hip_bf16.h>

constexpr int Bt  = 131072;
constexpr int OBS = 194;
constexpr int Hd  = 64;
constexpr int NT  = 256;   // 4 waves / block
constexpr int MT  = 128;   // rows per block (32 per wave)
constexpr int KP  = 200;   // Wt1 row stride (bf16 elems): 194 data + 6 zero pad (kb=6 b128 covers k192..199)
constexpr int WS  = 72;    // W2t / WhB row stride
constexpr int HS  = 72;    // hbuf row stride
constexpr int LS  = 18;    // logit buffer row stride

typedef short bf8   __attribute__((ext_vector_type(8)));
typedef float f32x4 __attribute__((ext_vector_type(4)));

__device__ __forceinline__ short f2bs(float f) {
    union { __hip_bfloat16 h; short s; } u;
    u.h = __float2bfloat16(f);
    return u.s;
}
__device__ __forceinline__ float bs2f(short s) {
    union { short s; __hip_bfloat16 h; } u;
    u.s = s;
    return __bfloat162float(u.h);
}
__device__ __forceinline__ float fast_tanh(float v) {
    v = fminf(fmaxf(v, -15.f), 15.f);
    float e = __expf(2.f * v);
    return (e - 1.f) * __builtin_amdgcn_rcpf(e + 1.f);
}

__global__ void __launch_bounds__(NT) fused_ac(
    const float* __restrict__ x, const int* __restrict__ act_in,
    const float* __restrict__ W1, const float* __restrict__ b1,
    const float* __restrict__ W2, const float* __restrict__ b2,
    const float* __restrict__ Wh, const float* __restrict__ bh,
    const float* __restrict__ Wc1, const float* __restrict__ bc1,
    const float* __restrict__ Wc2, const float* __restrict__ bc2,
    const float* __restrict__ Wc3, const float* __restrict__ bc3,
    float* __restrict__ out)
{
    __shared__ __align__(16) short Wt1[64 * KP];      // 25600 B  W(1|c1)^T bf16
    __shared__ __align__(16) short W2t[64 * WS];      //  9216 B  W(2|c2)^T bf16
    __shared__ __align__(16) short WhB[16 * WS];      //  2304 B  cols 0-14: Wh, col 15: Wc3
    __shared__ __align__(16) short hbuf[4][32 * HS];  // 18432 B  per-wave h / feat (A-layout, bf16)
    __shared__ short logitb[4][32 * LS];              //  4608 B  per-wave all-event logits
    __shared__ float resb[3][MT];                     //  1536 B  logp / ent / value
    // total 61696 B (< 64 KB)

    const int t  = threadIdx.x;
    const int w  = t >> 6;
    const int l  = t & 63;
    const int q  = l >> 4;   // quad
    const int c  = l & 15;
    const int b0 = blockIdx.x * MT;

    // ---------- zero pad (disjoint from staged regions; one barrier covers all) ----------
    if (t < 64) {
        int base = t * KP + 194;
        #pragma unroll
        for (int i = 0; i < 6; ++i) Wt1[base + i] = 0;
    }

    // ---------- weight staging: W[k][n] fp32 -> Wt[n][k] bf16 ----------
    auto stage = [&](const float* Wa, const float* Wb) {
        #pragma unroll 1
        for (int ch = t; ch < (OBS * Hd) / 4; ch += NT) {   // 3104 float4 chunks
            float4 v = reinterpret_cast<const float4*>(Wa)[ch];
            int f = ch * 4, k = f >> 6, n = f & 63;
            Wt1[(n    ) * KP + k] = f2bs(v.x);
            Wt1[(n + 1) * KP + k] = f2bs(v.y);
            Wt1[(n + 2) * KP + k] = f2bs(v.z);
            Wt1[(n + 3) * KP + k] = f2bs(v.w);
        }
        #pragma unroll 1
        for (int ch = t; ch < (Hd * Hd) / 4; ch += NT) {    // 1024 chunks
            float4 v = reinterpret_cast<const float4*>(Wb)[ch];
            int f = ch * 4, k = f >> 6, n = f & 63;
            W2t[(n    ) * WS + k] = f2bs(v.x);
            W2t[(n + 1) * WS + k] = f2bs(v.y);
            W2t[(n + 2) * WS + k] = f2bs(v.z);
            W2t[(n + 3) * WS + k] = f2bs(v.w);
        }
    };
    stage(W1, W2);
    #pragma unroll 1
    for (int i = t; i < 3 * Hd * 5; i += NT) {              // Wh[e][k][a] -> WhB[e*5+a][k]
        int e = i / 320, r2 = i - e * 320, k = r2 / 5, a = r2 - k * 5;
        WhB[(e * 5 + a) * WS + k] = f2bs(Wh[i]);
    }
    if (t < 64) WhB[15 * WS + t] = f2bs(Wc3[t]);            // value column
    __syncthreads();

    // ---------- x -> A-fragments (bf16), loaded ONCE, reused actor+critic ----------
    // A layout: lane holds A[m = c][k = q*8 + j]; two 16-row sets per wave.
    bf8 af[2][7];
    {
        const size_t row0 = (size_t)(b0 + w * 32 + c) * OBS;
        #pragma unroll
        for (int s = 0; s < 2; ++s) {
            const float* xr = x + row0 + (size_t)(s * 16) * OBS;
            #pragma unroll
            for (int kb = 0; kb < 6; ++kb) {
                const float2* p = reinterpret_cast<const float2*>(xr + kb * 32 + q * 8);
                float2 v0 = p[0], v1 = p[1], v2 = p[2], v3 = p[3];
                bf8 a;
                a[0] = f2bs(v0.x); a[1] = f2bs(v0.y); a[2] = f2bs(v1.x); a[3] = f2bs(v1.y);
                a[4] = f2bs(v2.x); a[5] = f2bs(v2.y); a[6] = f2bs(v3.x); a[7] = f2bs(v3.y);
                af[s][kb] = a;
            }
            bf8 a6 = {0, 0, 0, 0, 0, 0, 0, 0};
            if (q == 0) {                                   // k = 192,193 only
                float2 v = *reinterpret_cast<const float2*>(xr + 192);
                a6[0] = f2bs(v.x); a6[1] = f2bs(v.y);
            }
            af[s][6] = a6;
        }
    }

    short* hw = hbuf[w];

    // ---------- 2-layer trunk: feat = tanh(tanh(x@Wa+ba)@Wb+bb) -> hbuf ----------
    auto trunk = [&](const float* __restrict__ ba, const float* __restrict__ bb) {
        f32x4 acc[2][4];
        #pragma unroll
        for (int s = 0; s < 2; ++s)
            #pragma unroll
            for (int nt = 0; nt < 4; ++nt) acc[s][nt] = f32x4{0.f, 0.f, 0.f, 0.f};
        #pragma unroll
        for (int kb = 0; kb < 7; ++kb) {
            #pragma unroll
            for (int nt = 0; nt < 4; ++nt) {
                bf8 bw;
                if (kb < 6)
                    bw = *reinterpret_cast<const bf8*>(&Wt1[(nt * 16 + c) * KP + kb * 32 + q * 8]);
                else if (q == 0)
                    bw = *reinterpret_cast<const bf8*>(&Wt1[(nt * 16 + c) * KP + 192]);
                else
                    bw = bf8{0, 0, 0, 0, 0, 0, 0, 0};
                acc[0][nt] = __builtin_amdgcn_mfma_f32_16x16x32_bf16(af[0][kb], bw, acc[0][nt], 0, 0, 0);
                acc[1][nt] = __builtin_amdgcn_mfma_f32_16x16x32_bf16(af[1][kb], bw, acc[1][nt], 0, 0, 0);
            }
        }
        // D layout: lane holds D[row = q*4+r (+16s)][col = nt*16+c]
        #pragma unroll
        for (int nt = 0; nt < 4; ++nt) {
            float bias = ba[nt * 16 + c];
            #pragma unroll
            for (int s = 0; s < 2; ++s)
                #pragma unroll
                for (int r = 0; r < 4; ++r)
                    hw[(s * 16 + q * 4 + r) * HS + nt * 16 + c] = f2bs(fast_tanh(acc[s][nt][r] + bias));
        }
        #pragma unroll
        for (int s = 0; s < 2; ++s)
            #pragma unroll
            for (int nt = 0; nt < 4; ++nt) acc[s][nt] = f32x4{0.f, 0.f, 0.f, 0.f};
        #pragma unroll
        for (int kb = 0; kb < 2; ++kb) {
            bf8 ha[2];
            #pragma unroll
            for (int s = 0; s < 2; ++s)
                ha[s] = *reinterpret_cast<const bf8*>(&hw[(s * 16 + c) * HS + kb * 32 + q * 8]);
            #pragma unroll
            for (int nt = 0; nt < 4; ++nt) {
                bf8 bw = *reinterpret_cast<const bf8*>(&W2t[(nt * 16 + c) * WS + kb * 32 + q * 8]);
                acc[0][nt] = __builtin_amdgcn_mfma_f32_16x16x32_bf16(ha[0], bw, acc[0][nt], 0, 0, 0);
                acc[1][nt] = __builtin_amdgcn_mfma_f32_16x16x32_bf16(ha[1], bw, acc[1][nt], 0, 0, 0);
            }
        }
        #pragma unroll
        for (int nt = 0; nt < 4; ++nt) {
            float bias = bb[nt * 16 + c];
            #pragma unroll
            for (int s = 0; s < 2; ++s)
                #pragma unroll
                for (int r = 0; r < 4; ++r)
                    hw[(s * 16 + q * 4 + r) * HS + nt * 16 + c] = f2bs(fast_tanh(acc[s][nt][r] + bias));
        }
    };

    // feat[32x64] @ WhB[64x16]: cols 0-14 = per-event logits, col 15 = value
    auto smallmm = [&](f32x4 (&lacc)[2]) {
        lacc[0] = f32x4{0.f, 0.f, 0.f, 0.f};
        lacc[1] = f32x4{0.f, 0.f, 0.f, 0.f};
        #pragma unroll
        for (int kb = 0; kb < 2; ++kb) {
            bf8 bw = *reinterpret_cast<const bf8*>(&WhB[c * WS + kb * 32 + q * 8]);
            #pragma unroll
            for (int s = 0; s < 2; ++s) {
                bf8 fa = *reinterpret_cast<const bf8*>(&hw[(s * 16 + c) * HS + kb * 32 + q * 8]);
                lacc[s] = __builtin_amdgcn_mfma_f32_16x16x32_bf16(fa, bw, lacc[s], 0, 0, 0);
            }
        }
    };

    // ================= actor =================
    trunk(b1, b2);
    {
        f32x4 lg2[2];
        smallmm(lg2);
        short* lw = logitb[w];
        #pragma unroll
        for (int s = 0; s < 2; ++s)
            #pragma unroll
            for (int r = 0; r < 4; ++r)
                lw[(s * 16 + q * 4 + r) * LS + c] = f2bs(lg2[s][r]);

        // per-row softmax (wave-local; lanes 2x redundant over m = l&31)
        int m  = l & 31;
        int gm = b0 + w * 32 + m;
        const float* xr = x + (size_t)gm * OBS;
        float x0 = xr[0], x1 = xr[1], x2 = xr[2];
        int ev = 0; float best = x0;
        if (x1 > best) { best = x1; ev = 1; }
        if (x2 > best) { ev = 2; }
        float lg[5];
        #pragma unroll
        for (int a = 0; a < 5; ++a)
            lg[a] = bs2f(lw[m * LS + ev * 5 + a]) + bh[ev * 5 + a];
        float mx = lg[0];
        #pragma unroll
        for (int a = 1; a < 5; ++a) mx = fmaxf(mx, lg[a]);
        float se = 0.f;
        #pragma unroll
        for (int a = 0; a < 5; ++a) se += __expf(lg[a] - mx);
        float lse = __logf(se) + mx;
        int act = act_in[gm];
        float lsel = lg[0];
        #pragma unroll
        for (int a = 1; a < 5; ++a) lsel = (act == a) ? lg[a] : lsel;
        float ent = 0.f;
        #pragma unroll
        for (int a = 0; a < 5; ++a) { float lp = lg[a] - lse; ent -= __expf(lp) * lp; }
        if (l < 32) { resb[0][w * 32 + m] = lsel - lse; resb[1][w * 32 + m] = ent; }
    }

    // ================= critic (restage weights into same LDS) =================
    __syncthreads();
    stage(Wc1, Wc2);
    __syncthreads();

    trunk(bc1, bc2);
    {
        f32x4 vacc[2];
        smallmm(vacc);
        if (c == 15) {                      // D col 15 = feat_c . Wc3
            float bc3v = bc3[0];
            #pragma unroll
            for (int s = 0; s < 2; ++s)
                #pragma unroll
                for (int r = 0; r < 4; ++r)
                    resb[2][w * 32 + s * 16 + q * 4 + r] = vacc[s][r] + bc3v;
        }
    }

    __syncthreads();
    if (t < MT) {
        int b = b0 + t;
        out[b]          = (float)act_in[b];
        out[Bt + b]     = resb[0][t];
        out[2 * Bt + b] = resb[1][t];
        out[3 * Bt + b] = resb[2][t];
    }
}

extern "C" void kernel_launch(void* const* d_in, const int* in_sizes, int n_in,
                              void* d_out, int out_size, void* d_ws, size_t ws_size,
                              hipStream_t stream) {
    const float* x   = (const float*)d_in[0];
    const int*   act = (const int*)  d_in[1];
    const float* W1  = (const float*)d_in[2];
    const float* b1  = (const float*)d_in[3];
    const float* W2  = (const float*)d_in[4];
    const float* b2  = (const float*)d_in[5];
    const float* Wh  = (const float*)d_in[6];
    const float* bh  = (const float*)d_in[7];
    const float* Wc1 = (const float*)d_in[8];
    const float* bc1 = (const float*)d_in[9];
    const float* Wc2 = (const float*)d_in[10];
    const float* bc2 = (const float*)d_in[11];
    const float* Wc3 = (const float*)d_in[12];
    const float* bc3 = (const float*)d_in[13];
    float* out = (float*)d_out;

    dim3 grid(Bt / MT), block(NT);
    hipLaunchKernelGGL(fused_ac, grid, block, 0, stream,
                       x, act, W1, b1, W2, b2, Wh, bh,
                       Wc1, bc1, Wc2, bc2, Wc3, bc3, out);
}

// Round 3
// 199.883 us; speedup vs baseline: 3.9169x; 1.0607x over previous
//
#include <hip/hip_runtime.h>
#include <hip/hip_bf16.h>

constexpr int Bt  = 131072;
constexpr int OBS = 194;
constexpr int Hd  = 64;
constexpr int NT  = 256;   // 4 waves / block
constexpr int MT  = 128;   // rows per block (32 per wave)
constexpr int HS  = 72;    // hbuf row stride (shorts): 16B-aligned, 2-way bank alias only (free)
constexpr int LS  = 18;    // logit buffer row stride

// d_ws layout (shorts): B-fragment layouts for mfma_f32_16x16x32_bf16.
// Frag addressing: frag_base[(kb*NTILES + nt)*64 + lane], 8 shorts each;
// value j of lane l = W[k = kb*32 + (l>>4)*8 + j][n = nt*16 + (l&15)], zero-padded k>=194.
constexpr int W1B_OFF  = 0;       // 7 kb * 4 nt * 64 * 8 = 28672
constexpr int WC1B_OFF = 28672;
constexpr int W2B_OFF  = 57344;   // 2 kb * 4 nt * 64 * 8 = 8192
constexpr int WC2B_OFF = 65536;
constexpr int WHB_OFF  = 73728;   // 2 kb * 1 nt * 64 * 8 = 1024 (cols 0-14: Wh, col 15: Wc3)
constexpr int WS_SHORTS = 74752;  // 149504 bytes total

typedef short bf8   __attribute__((ext_vector_type(8)));
typedef float f32x4 __attribute__((ext_vector_type(4)));

__device__ __forceinline__ short f2bs(float f) {
    union { __hip_bfloat16 h; short s; } u;
    u.h = __float2bfloat16(f);
    return u.s;
}
__device__ __forceinline__ float bs2f(short s) {
    union { short s; __hip_bfloat16 h; } u;
    u.s = s;
    return __bfloat162float(u.h);
}
__device__ __forceinline__ float fast_tanh(float v) {
    v = fminf(fmaxf(v, -15.f), 15.f);
    float e = __expf(2.f * v);
    return (e - 1.f) * __builtin_amdgcn_rcpf(e + 1.f);
}

// ---------------- prep: convert weights -> B-fragment layout in d_ws ----------------
__global__ void __launch_bounds__(256) prep(
    const float* __restrict__ W1, const float* __restrict__ W2,
    const float* __restrict__ Wh, const float* __restrict__ Wc1,
    const float* __restrict__ Wc2, const float* __restrict__ Wc3,
    short* __restrict__ ws)
{
    const int gid = blockIdx.x * 256 + threadIdx.x;
    const int gsz = gridDim.x * 256;

    // W1B / Wc1B: i = ((kb*4 + nt)*64 + l)*8 + j
    for (int i = gid; i < 28672; i += gsz) {
        int j = i & 7, l = (i >> 3) & 63, nt = (i >> 9) & 3, kb = i >> 11;
        int k = kb * 32 + ((l >> 4) << 3) + j;
        int n = nt * 16 + (l & 15);
        short v1 = 0, v2 = 0;
        if (k < OBS) {
            v1 = f2bs(W1[k * 64 + n]);
            v2 = f2bs(Wc1[k * 64 + n]);
        }
        ws[W1B_OFF + i]  = v1;
        ws[WC1B_OFF + i] = v2;
    }
    // W2B / Wc2B
    for (int i = gid; i < 8192; i += gsz) {
        int j = i & 7, l = (i >> 3) & 63, nt = (i >> 9) & 3, kb = i >> 11;
        int k = kb * 32 + ((l >> 4) << 3) + j;
        int n = nt * 16 + (l & 15);
        ws[W2B_OFF + i]  = f2bs(W2[k * 64 + n]);
        ws[WC2B_OFF + i] = f2bs(Wc2[k * 64 + n]);
    }
    // WhB: cols 0-14 = Wh[e][k][a] (col = e*5+a), col 15 = Wc3[k]
    for (int i = gid; i < 1024; i += gsz) {
        int j = i & 7, l = (i >> 3) & 63, kb = i >> 9;
        int k = kb * 32 + ((l >> 4) << 3) + j;
        int cc = l & 15;
        float v;
        if (cc == 15) v = Wc3[k];
        else { int e = cc / 5, a = cc - 5 * e; v = Wh[(e * 64 + k) * 5 + a]; }
        ws[WHB_OFF + i] = f2bs(v);
    }
}

// ---------------- main fused kernel: no barriers, no LDS staging ----------------
__global__ void __launch_bounds__(NT, 4) fused_ac(
    const float* __restrict__ x, const int* __restrict__ act_in,
    const float* __restrict__ b1, const float* __restrict__ b2,
    const float* __restrict__ bh, const float* __restrict__ bc1,
    const float* __restrict__ bc2, const float* __restrict__ bc3,
    const short* __restrict__ ws,
    float* __restrict__ out)
{
    __shared__ __align__(16) short hbuf[4][32 * HS];   // 18432 B per-wave h/feat (A-layout)
    __shared__ short logitb[4][32 * LS];               //  4608 B per-wave all-event logits
    __shared__ float valb[4][32];                      //   512 B per-wave value
    // total 23552 B -> 4 blocks/CU at launch_bounds(256,4)

    const int t  = threadIdx.x;
    const int w  = t >> 6;
    const int l  = t & 63;
    const int q  = l >> 4;
    const int c  = l & 15;
    const int b0 = blockIdx.x * MT;

    const bf8* __restrict__ fW1  = reinterpret_cast<const bf8*>(ws + W1B_OFF);
    const bf8* __restrict__ fWc1 = reinterpret_cast<const bf8*>(ws + WC1B_OFF);
    const bf8* __restrict__ fW2  = reinterpret_cast<const bf8*>(ws + W2B_OFF);
    const bf8* __restrict__ fWc2 = reinterpret_cast<const bf8*>(ws + WC2B_OFF);
    const bf8* __restrict__ fWh  = reinterpret_cast<const bf8*>(ws + WHB_OFF);

    // ---------- x -> A-fragments (bf16), loaded ONCE, reused actor+critic ----------
    bf8 af[2][7];
    {
        const size_t row0 = (size_t)(b0 + w * 32 + c) * OBS;
        #pragma unroll
        for (int s = 0; s < 2; ++s) {
            const float* xr = x + row0 + (size_t)(s * 16) * OBS;
            #pragma unroll
            for (int kb = 0; kb < 6; ++kb) {
                const float2* p = reinterpret_cast<const float2*>(xr + kb * 32 + q * 8);
                float2 v0 = p[0], v1 = p[1], v2 = p[2], v3 = p[3];
                bf8 a;
                a[0] = f2bs(v0.x); a[1] = f2bs(v0.y); a[2] = f2bs(v1.x); a[3] = f2bs(v1.y);
                a[4] = f2bs(v2.x); a[5] = f2bs(v2.y); a[6] = f2bs(v3.x); a[7] = f2bs(v3.y);
                af[s][kb] = a;
            }
            bf8 a6 = {0, 0, 0, 0, 0, 0, 0, 0};
            if (q == 0) {                      // k = 192,193 only (B is zero-padded past 194)
                float2 v = *reinterpret_cast<const float2*>(xr + 192);
                a6[0] = f2bs(v.x); a6[1] = f2bs(v.y);
            }
            af[s][6] = a6;
        }
    }

    short* hw = hbuf[w];

    // ---------- trunk: feat = tanh(tanh(x@Wa+ba)@Wb+bb) -> hbuf (bf16, A-layout) ----------
    auto trunk = [&](const bf8* __restrict__ fa1, const bf8* __restrict__ fa2,
                     const float* __restrict__ ba, const float* __restrict__ bb) {
        f32x4 acc[2][4];
        #pragma unroll
        for (int s = 0; s < 2; ++s)
            #pragma unroll
            for (int nt = 0; nt < 4; ++nt) acc[s][nt] = f32x4{0.f, 0.f, 0.f, 0.f};
        #pragma unroll
        for (int kb = 0; kb < 7; ++kb) {
            #pragma unroll
            for (int nt = 0; nt < 4; ++nt) {
                bf8 bw = fa1[(kb * 4 + nt) * 64 + l];
                acc[0][nt] = __builtin_amdgcn_mfma_f32_16x16x32_bf16(af[0][kb], bw, acc[0][nt], 0, 0, 0);
                acc[1][nt] = __builtin_amdgcn_mfma_f32_16x16x32_bf16(af[1][kb], bw, acc[1][nt], 0, 0, 0);
            }
        }
        // D layout: lane holds D[row = q*4+r (+16s)][col = nt*16+c]
        #pragma unroll
        for (int nt = 0; nt < 4; ++nt) {
            float bias = ba[nt * 16 + c];
            #pragma unroll
            for (int s = 0; s < 2; ++s)
                #pragma unroll
                for (int r = 0; r < 4; ++r)
                    hw[(s * 16 + q * 4 + r) * HS + nt * 16 + c] = f2bs(fast_tanh(acc[s][nt][r] + bias));
        }
        #pragma unroll
        for (int s = 0; s < 2; ++s)
            #pragma unroll
            for (int nt = 0; nt < 4; ++nt) acc[s][nt] = f32x4{0.f, 0.f, 0.f, 0.f};
        #pragma unroll
        for (int kb = 0; kb < 2; ++kb) {
            bf8 ha[2];
            #pragma unroll
            for (int s = 0; s < 2; ++s)
                ha[s] = *reinterpret_cast<const bf8*>(&hw[(s * 16 + c) * HS + kb * 32 + q * 8]);
            #pragma unroll
            for (int nt = 0; nt < 4; ++nt) {
                bf8 bw = fa2[(kb * 4 + nt) * 64 + l];
                acc[0][nt] = __builtin_amdgcn_mfma_f32_16x16x32_bf16(ha[0], bw, acc[0][nt], 0, 0, 0);
                acc[1][nt] = __builtin_amdgcn_mfma_f32_16x16x32_bf16(ha[1], bw, acc[1][nt], 0, 0, 0);
            }
        }
        #pragma unroll
        for (int nt = 0; nt < 4; ++nt) {
            float bias = bb[nt * 16 + c];
            #pragma unroll
            for (int s = 0; s < 2; ++s)
                #pragma unroll
                for (int r = 0; r < 4; ++r)
                    hw[(s * 16 + q * 4 + r) * HS + nt * 16 + c] = f2bs(fast_tanh(acc[s][nt][r] + bias));
        }
    };

    // feat[32x64] @ WhB[64x16] -> cols 0-14 per-event logits, col 15 value
    auto smallmm = [&](f32x4 (&lacc)[2]) {
        lacc[0] = f32x4{0.f, 0.f, 0.f, 0.f};
        lacc[1] = f32x4{0.f, 0.f, 0.f, 0.f};
        #pragma unroll
        for (int kb = 0; kb < 2; ++kb) {
            bf8 bw = fWh[kb * 64 + l];
            #pragma unroll
            for (int s = 0; s < 2; ++s) {
                bf8 fa = *reinterpret_cast<const bf8*>(&hw[(s * 16 + c) * HS + kb * 32 + q * 8]);
                lacc[s] = __builtin_amdgcn_mfma_f32_16x16x32_bf16(fa, bw, lacc[s], 0, 0, 0);
            }
        }
    };

    // ================= actor =================
    trunk(fW1, fW2, b1, b2);
    float r_logp, r_ent;
    {
        f32x4 lg2[2];
        smallmm(lg2);
        short* lw = logitb[w];
        #pragma unroll
        for (int s = 0; s < 2; ++s)
            #pragma unroll
            for (int r = 0; r < 4; ++r)
                lw[(s * 16 + q * 4 + r) * LS + c] = f2bs(lg2[s][r]);

        // per-row softmax (wave-local; lanes 32-63 redundant over m = l&31)
        int m  = l & 31;
        int gm = b0 + w * 32 + m;
        const float* xr = x + (size_t)gm * OBS;
        float x0 = xr[0], x1 = xr[1], x2 = xr[2];
        int ev = 0; float best = x0;
        if (x1 > best) { best = x1; ev = 1; }
        if (x2 > best) { ev = 2; }
        float lg[5];
        #pragma unroll
        for (int a = 0; a < 5; ++a)
            lg[a] = bs2f(lw[m * LS + ev * 5 + a]) + bh[ev * 5 + a];
        float mx = lg[0];
        #pragma unroll
        for (int a = 1; a < 5; ++a) mx = fmaxf(mx, lg[a]);
        float se = 0.f;
        #pragma unroll
        for (int a = 0; a < 5; ++a) se += __expf(lg[a] - mx);
        float lse = __logf(se) + mx;
        int act = act_in[gm];
        float lsel = lg[0];
        #pragma unroll
        for (int a = 1; a < 5; ++a) lsel = (act == a) ? lg[a] : lsel;
        float ent = 0.f;
        #pragma unroll
        for (int a = 0; a < 5; ++a) { float lp = lg[a] - lse; ent -= __expf(lp) * lp; }
        r_logp = lsel - lse;
        r_ent  = ent;
    }

    // ================= critic =================
    trunk(fWc1, fWc2, bc1, bc2);
    {
        f32x4 vacc[2];
        smallmm(vacc);
        if (c == 15) {                       // D col 15 = feat . Wc3
            float bc3v = bc3[0];
            #pragma unroll
            for (int s = 0; s < 2; ++s)
                #pragma unroll
                for (int r = 0; r < 4; ++r)
                    valb[w][s * 16 + q * 4 + r] = vacc[s][r] + bc3v;
        }
    }

    // ---------------- outputs: per-wave coalesced 128B segments ----------------
    if (l < 32) {
        int gm = b0 + w * 32 + l;
        out[gm]          = (float)act_in[gm];
        out[Bt + gm]     = r_logp;
        out[2 * Bt + gm] = r_ent;
        out[3 * Bt + gm] = valb[w][l];
    }
}

extern "C" void kernel_launch(void* const* d_in, const int* in_sizes, int n_in,
                              void* d_out, int out_size, void* d_ws, size_t ws_size,
                              hipStream_t stream) {
    const float* x   = (const float*)d_in[0];
    const int*   act = (const int*)  d_in[1];
    const float* W1  = (const float*)d_in[2];
    const float* b1  = (const float*)d_in[3];
    const float* W2  = (const float*)d_in[4];
    const float* b2  = (const float*)d_in[5];
    const float* Wh  = (const float*)d_in[6];
    const float* bh  = (const float*)d_in[7];
    const float* Wc1 = (const float*)d_in[8];
    const float* bc1 = (const float*)d_in[9];
    const float* Wc2 = (const float*)d_in[10];
    const float* bc2 = (const float*)d_in[11];
    const float* Wc3 = (const float*)d_in[12];
    const float* bc3 = (const float*)d_in[13];
    float* out = (float*)d_out;
    short* ws  = (short*)d_ws;

    hipLaunchKernelGGL(prep, dim3(64), dim3(256), 0, stream,
                       W1, W2, Wh, Wc1, Wc2, Wc3, ws);
    hipLaunchKernelGGL(fused_ac, dim3(Bt / MT), dim3(NT), 0, stream,
                       x, act, b1, b2, bh, bc1, bc2, bc3, ws, out);
}